// Round 4
// baseline (156.652 us; speedup 1.0000x reference)
//
#include <hip/hip_runtime.h>
#include <hip/hip_bf16.h>
#include <stdint.h>

#define N    8192
#define D    256
#define NCLS 100

static constexpr float TEMP    = 0.5f;
static constexpr float SCALE_F = 1.69864360f;  // sqrt(log2e/TEMP)
static constexpr float E2      = 7.38905609893065f;
static constexpr float LN2     = 0.69314718055994531f;

typedef __bf16 bf16x8 __attribute__((ext_vector_type(8)));
typedef float  f32x16 __attribute__((ext_vector_type(16)));

__device__ __forceinline__ unsigned short f2bf(float f) {
  union { float f; unsigned int u; } x; x.f = f;
  unsigned int r = x.u + 0x7fffu + ((x.u >> 16) & 1u);
  return (unsigned short)(r >> 16);
}
__device__ __forceinline__ float bf2f(unsigned short b) {
  union { unsigned int u; float f; } x; x.u = ((unsigned int)b) << 16;
  return x.f;
}
__device__ __forceinline__ void gld16(const void* g, void* l) {
  __builtin_amdgcn_global_load_lds(
      (const __attribute__((address_space(1))) unsigned int*)g,
      (__attribute__((address_space(3))) unsigned int*)l, 16, 0, 0);
}

__global__ __launch_bounds__(256) void normalize_kernel(
    const float* __restrict__ emb, const long long* __restrict__ label,
    unsigned short* __restrict__ abf, int* __restrict__ cnt,
    int* __restrict__ list) {
  const int row  = blockIdx.x * 4 + (threadIdx.x >> 6);
  const int lane = threadIdx.x & 63;
  const float4 v = ((const float4*)(emb + (size_t)row * D))[lane];
  float ss = v.x * v.x + v.y * v.y + v.z * v.z + v.w * v.w;
#pragma unroll
  for (int off = 1; off < 64; off <<= 1) ss += __shfl_xor(ss, off);
  const float s = rsqrtf(ss) * SCALE_F;
  ushort4 o;
  o.x = f2bf(v.x * s); o.y = f2bf(v.y * s);
  o.z = f2bf(v.z * s); o.w = f2bf(v.w * s);
  ((ushort4*)(abf + (size_t)row * D))[lane] = o;
  if (lane == 0) {
    const int c = (int)label[row];
    const int slot = atomicAdd(cnt + c, 1);
    list[c * 256 + slot] = row;
  }
}

// ---- Kernel B: one upper-triangle 128x128 tile per block; 32x32x16 MFMA.
// Off-diagonal tiles also emit the transposed (column-sum) contribution.
#define TM 128
#define BK 64

__global__ __launch_bounds__(256, 4) void simexp_rowsum_kernel(
    const unsigned short* __restrict__ A, float* __restrict__ rowsum) {
  __shared__ __align__(16) unsigned short sa[TM * BK];
  __shared__ __align__(16) unsigned short sb[TM * BK];
  const int tid  = threadIdx.x;
  const int w    = tid >> 6;
  const int lane = tid & 63;
  const int l31  = lane & 31;
  const int half = lane >> 5;

  // linear id -> (bi, bj), bj >= bi; off(bi) = bi*(129-bi)/2
  const int id = blockIdx.x;
  int bi = (int)((129.0f - sqrtf(16641.0f - 8.0f * (float)id)) * 0.5f);
  while (bi > 0 && (bi * (129 - bi)) / 2 > id) --bi;
  while (((bi + 1) * (128 - bi)) / 2 <= id) ++bi;
  const int bj   = bi + (id - (bi * (129 - bi)) / 2);
  const int row0 = bi * TM;
  const int jb0  = bj * TM;
  const bool diag = (bi == bj);

  const int wm   = (w & 1) * 64;
  const int wn   = (w >> 1) * 64;
  const int srow = lane >> 3;                   // 0..7
  const int scol = (((lane & 7) ^ srow) << 3);  // XOR-swizzled 16B block

  f32x16 acc[2][2];
#pragma unroll
  for (int mt = 0; mt < 2; ++mt)
#pragma unroll
    for (int nt = 0; nt < 2; ++nt)
#pragma unroll
      for (int r = 0; r < 16; ++r) acc[mt][nt][r] = 0.f;

  for (int kc = 0; kc < D; kc += BK) {
#pragma unroll
    for (int p = 0; p < 4; ++p) {
      const int seg = p * 4 + w;          // wave-uniform 0..15
      const int r   = seg * 8 + srow;
      gld16(A + (size_t)(row0 + r) * D + kc + scol, sa + seg * 512);
      gld16(A + (size_t)(jb0 + r) * D + kc + scol, sb + seg * 512);
    }
    __syncthreads();
#pragma unroll
    for (int ks = 0; ks < 4; ++ks) {            // K-steps of 16
      const int kb = ks * 2 + half;             // 16B block 0..7
      const int sw = ((kb ^ (l31 & 7)) << 3);
      bf16x8 af[2], bfr[2];
#pragma unroll
      for (int mt = 0; mt < 2; ++mt)
        af[mt] = *(const bf16x8*)(sa + ((wm + mt * 32 + l31) << 6) + sw);
#pragma unroll
      for (int nt = 0; nt < 2; ++nt)
        bfr[nt] = *(const bf16x8*)(sb + ((wn + nt * 32 + l31) << 6) + sw);
#pragma unroll
      for (int mt = 0; mt < 2; ++mt)
#pragma unroll
        for (int nt = 0; nt < 2; ++nt)
          acc[mt][nt] = __builtin_amdgcn_mfma_f32_32x32x16_bf16(
              af[mt], bfr[nt], acc[mt][nt], 0, 0, 0);
    }
    __syncthreads();
  }

  // Epilogue. C layout (32x32): col = lane&31, row = (r&3)+8*(r>>2)+4*half.
  float cs[2] = {0.f, 0.f};
#pragma unroll
  for (int mt = 0; mt < 2; ++mt) {
    float rp[16];
#pragma unroll
    for (int nt = 0; nt < 2; ++nt)
#pragma unroll
      for (int r = 0; r < 16; ++r) {
        const float v = __builtin_amdgcn_exp2f(acc[mt][nt][r]);
        if (nt == 0) rp[r] = v; else rp[r] += v;
        cs[nt] += v;
      }
#pragma unroll
    for (int r = 0; r < 16; ++r) {
      float v = rp[r];
      v += __shfl_xor(v, 1);
      v += __shfl_xor(v, 2);
      v += __shfl_xor(v, 4);
      v += __shfl_xor(v, 8);
      v += __shfl_xor(v, 16);
      if (l31 == 0)
        atomicAdd(&rowsum[row0 + wm + mt * 32 + (r & 3) + 8 * (r >> 2) +
                          4 * half],
                  v);
    }
  }
  if (!diag) {
#pragma unroll
    for (int nt = 0; nt < 2; ++nt) {
      float v = cs[nt];
      v += __shfl_xor(v, 32);
      if (half == 0)
        atomicAdd(&rowsum[jb0 + wn + nt * 32 + l31], v);
    }
  }
}

__global__ __launch_bounds__(256) void finalize_kernel(
    const unsigned short* __restrict__ abf, const float* __restrict__ rowsum,
    const long long* __restrict__ label, const int* __restrict__ cnt,
    const int* __restrict__ list, float* __restrict__ out) {
  __shared__ float red[4];
  __shared__ int rows_l[256];
  const int tid  = threadIdx.x;
  const int w    = tid >> 6;
  const int lane = tid & 63;

  if (blockIdx.x < NCLS) {
    const int c = blockIdx.x;
    const int m = cnt[c];
    if (m <= 1) return;
    if (tid < m) rows_l[tid] = list[c * 256 + tid];
    __syncthreads();
    float acc = 0.f;
    for (int s = 0; s < m; ++s)
      acc += bf2f(abf[(size_t)rows_l[s] * D + tid]);
    float v = acc * acc;
#pragma unroll
    for (int off = 1; off < 64; off <<= 1) v += __shfl_xor(v, off);
    if (lane == 0) red[w] = v;
    __syncthreads();
    if (tid == 0) {
      const float ssq = red[0] + red[1] + red[2] + red[3];
      const float term = (ssq * LN2 - 2.0f * (float)m) / (float)(m - 1);
      atomicAdd(out, -term);
    }
  } else {
    const int i = (blockIdx.x - NCLS) * 256 + tid;
    const int c = (int)label[i];
    float v = 0.f;
    if (cnt[c] > 1)
      v = __builtin_amdgcn_logf(rowsum[i] - E2) * LN2;
#pragma unroll
    for (int off = 1; off < 64; off <<= 1) v += __shfl_xor(v, off);
    if (lane == 0) red[w] = v;
    __syncthreads();
    if (tid == 0)
      atomicAdd(out, red[0] + red[1] + red[2] + red[3]);
  }
}

extern "C" void kernel_launch(void* const* d_in, const int* in_sizes, int n_in,
                              void* d_out, int out_size, void* d_ws,
                              size_t ws_size, hipStream_t stream) {
  const float* emb = (const float*)d_in[0];
  const long long* label = (const long long*)d_in[1];
  float* out = (float*)d_out;

  char* ws = (char*)d_ws;
  unsigned short* abf = (unsigned short*)ws;           // 4 MB
  float* rowsum = (float*)(ws + (size_t)N * D * 2);    // N floats
  int* cnt = (int*)(rowsum + N);                       // 128 ints (100 used)
  int* list = cnt + 128;                               // NCLS*256 ints

  hipMemsetAsync(rowsum, 0, (size_t)N * 4 + 128 * 4, stream);
  hipMemsetAsync(out, 0, sizeof(float), stream);

  normalize_kernel<<<N / 4, 256, 0, stream>>>(emb, label, abf, cnt, list);

  // upper-triangle tiles: 64*65/2 = 2080 blocks, one 128x128 tile each
  simexp_rowsum_kernel<<<2080, 256, 0, stream>>>(abf, rowsum);

  finalize_kernel<<<NCLS + N / 256, 256, 0, stream>>>(abf, rowsum, label, cnt,
                                                      list, out);
}

// Round 5
// 137.883 us; speedup vs baseline: 1.1361x; 1.1361x over previous
//
#include <hip/hip_runtime.h>
#include <hip/hip_bf16.h>
#include <stdint.h>

#define N    8192
#define D    256
#define NCLS 100

static constexpr float TEMP    = 0.5f;
static constexpr float SCALE_F = 1.69864360f;  // sqrt(log2e/TEMP)
static constexpr float E2      = 7.38905609893065f;
static constexpr float LN2     = 0.69314718055994531f;

typedef __bf16 bf16x8 __attribute__((ext_vector_type(8)));
typedef float  f32x4  __attribute__((ext_vector_type(4)));

__device__ __forceinline__ unsigned short f2bf(float f) {
  union { float f; unsigned int u; } x; x.f = f;
  unsigned int r = x.u + 0x7fffu + ((x.u >> 16) & 1u);
  return (unsigned short)(r >> 16);
}
__device__ __forceinline__ float bf2f(unsigned short b) {
  union { unsigned int u; float f; } x; x.u = ((unsigned int)b) << 16;
  return x.f;
}
__device__ __forceinline__ void gld16(const void* g, void* l) {
  __builtin_amdgcn_global_load_lds(
      (const __attribute__((address_space(1))) unsigned int*)g,
      (__attribute__((address_space(3))) unsigned int*)l, 16, 0, 0);
}

__global__ __launch_bounds__(256) void normalize_kernel(
    const float* __restrict__ emb, const long long* __restrict__ label,
    unsigned short* __restrict__ abf, int* __restrict__ cnt,
    int* __restrict__ list) {
  const int row  = blockIdx.x * 4 + (threadIdx.x >> 6);
  const int lane = threadIdx.x & 63;
  const float4 v = ((const float4*)(emb + (size_t)row * D))[lane];
  float ss = v.x * v.x + v.y * v.y + v.z * v.z + v.w * v.w;
#pragma unroll
  for (int off = 1; off < 64; off <<= 1) ss += __shfl_xor(ss, off);
  const float s = rsqrtf(ss) * SCALE_F;
  ushort4 o;
  o.x = f2bf(v.x * s); o.y = f2bf(v.y * s);
  o.z = f2bf(v.z * s); o.w = f2bf(v.w * s);
  ((ushort4*)(abf + (size_t)row * D))[lane] = o;
  if (lane == 0) {
    const int c = (int)label[row];
    const int slot = atomicAdd(cnt + c, 1);
    list[c * 256 + slot] = row;
  }
}

// ---- Kernel B: one 128x128 upper-triangle tile per block. A-fragments live
// in registers (loaded straight from L2); B-tile staged to LDS ONCE for the
// full K=256 -> a single barrier per block, no per-round vmcnt(0) drains.
#define TM 128

__global__ __launch_bounds__(256) void simexp_rowsum_kernel(
    const unsigned short* __restrict__ A, float* __restrict__ rowsum) {
  __shared__ __align__(16) unsigned short sb[TM * D];  // 64 KB
  const int tid  = threadIdx.x;
  const int w    = tid >> 6;
  const int lane = tid & 63;
  const int quad = lane >> 4;
  const int l15  = lane & 15;

  // linear id -> (bi, bj), bj >= bi
  const int id = blockIdx.x;
  int bi = (int)((129.0f - sqrtf(16641.0f - 8.0f * (float)id)) * 0.5f);
  while (bi > 0 && (bi * (129 - bi)) / 2 > id) --bi;
  while (((bi + 1) * (128 - bi)) / 2 <= id) ++bi;
  const int bj   = bi + (id - (bi * (129 - bi)) / 2);
  const int row0 = bi * TM;
  const int jb0  = bj * TM;
  const bool diag = (bi == bj);

  // A-fragments to registers: wave w owns rows w*32 .. w*32+31.
  // A-layout: m = l15 (row), k = ks*32 + quad*8 + j
  bf16x8 af[2][8];
#pragma unroll
  for (int mt = 0; mt < 2; ++mt)
#pragma unroll
    for (int ks = 0; ks < 8; ++ks)
      af[mt][ks] = *(const bf16x8*)(
          A + (size_t)(row0 + w * 32 + mt * 16 + l15) * D + ks * 32 + quad * 8);

  // Stage full B-tile (128 rows x 256 cols), 16B-block-swizzled:
  // within each row-group of 8 blocks, position b holds source block b^(r&7).
  {
    const int b = lane & 31;   // 16B-block position within the 512B row
    const int g = b >> 3;
    const int h = lane >> 5;
#pragma unroll
    for (int t = 0; t < 16; ++t) {
      const int r = (t * 4 + w) * 2 + h;  // dest row 0..127
      const int src =
          (jb0 + r) * D + g * 64 + (((b & 7) ^ (r & 7)) << 3);
      gld16(A + src, sb + (t * 4 + w) * 512);
    }
  }
  __syncthreads();  // the ONE barrier

  f32x4 acc[2][8];
#pragma unroll
  for (int mt = 0; mt < 2; ++mt)
#pragma unroll
    for (int nt = 0; nt < 8; ++nt) acc[mt][nt] = (f32x4){0.f, 0.f, 0.f, 0.f};

#pragma unroll
  for (int ks = 0; ks < 8; ++ks) {
    bf16x8 bfr[8];
#pragma unroll
    for (int nt = 0; nt < 8; ++nt) {
      const int n = nt * 16 + l15;                      // B row (= col index)
      const int c = ((ks & 1) * 4 + quad) ^ (l15 & 7);  // swizzled 16B block
      bfr[nt] = *(const bf16x8*)(sb + n * D + (ks >> 1) * 64 + c * 8);
    }
#pragma unroll
    for (int mt = 0; mt < 2; ++mt)
#pragma unroll
      for (int nt = 0; nt < 8; ++nt)
        acc[mt][nt] = __builtin_amdgcn_mfma_f32_16x16x32_bf16(
            af[mt][ks], bfr[nt], acc[mt][nt], 0, 0, 0);
  }

  // Epilogue. C layout: col = l15, row-in-16 = quad*4 + e.
  float cs[8];
#pragma unroll
  for (int nt = 0; nt < 8; ++nt) cs[nt] = 0.f;
#pragma unroll
  for (int mt = 0; mt < 2; ++mt) {
    float rp[4] = {0.f, 0.f, 0.f, 0.f};
#pragma unroll
    for (int nt = 0; nt < 8; ++nt)
#pragma unroll
      for (int e = 0; e < 4; ++e) {
        const float v = __builtin_amdgcn_exp2f(acc[mt][nt][e]);
        rp[e] += v;
        cs[nt] += v;
      }
#pragma unroll
    for (int e = 0; e < 4; ++e) {
      float v = rp[e];
      v += __shfl_xor(v, 1);
      v += __shfl_xor(v, 2);
      v += __shfl_xor(v, 4);
      v += __shfl_xor(v, 8);
      if (l15 == 0)
        atomicAdd(&rowsum[row0 + w * 32 + mt * 16 + quad * 4 + e], v);
    }
  }

  // Column sums (symmetry): reduce per-wave over quads, then cross-wave
  // through LDS (sb is dead now), then 128 atomics for the whole block.
  if (!diag) {
    float* cred = (float*)sb;  // [4][128]
    __syncthreads();           // all waves done reading sb
#pragma unroll
    for (int nt = 0; nt < 8; ++nt) {
      float v = cs[nt];
      v += __shfl_xor(v, 16);
      v += __shfl_xor(v, 32);
      if (quad == 0) cred[w * 128 + nt * 16 + l15] = v;
    }
    __syncthreads();
    if (tid < 128)
      atomicAdd(&rowsum[jb0 + tid],
                cred[tid] + cred[128 + tid] + cred[256 + tid] +
                    cred[384 + tid]);
  }
}

__global__ __launch_bounds__(256) void finalize_kernel(
    const unsigned short* __restrict__ abf, const float* __restrict__ rowsum,
    const long long* __restrict__ label, const int* __restrict__ cnt,
    const int* __restrict__ list, float* __restrict__ out) {
  __shared__ float red[4];
  __shared__ int rows_l[256];
  const int tid  = threadIdx.x;
  const int w    = tid >> 6;
  const int lane = tid & 63;

  if (blockIdx.x < NCLS) {
    const int c = blockIdx.x;
    const int m = cnt[c];
    if (m <= 1) return;
    if (tid < m) rows_l[tid] = list[c * 256 + tid];
    __syncthreads();
    float acc = 0.f;
    for (int s = 0; s < m; ++s)
      acc += bf2f(abf[(size_t)rows_l[s] * D + tid]);
    float v = acc * acc;
#pragma unroll
    for (int off = 1; off < 64; off <<= 1) v += __shfl_xor(v, off);
    if (lane == 0) red[w] = v;
    __syncthreads();
    if (tid == 0) {
      const float ssq = red[0] + red[1] + red[2] + red[3];
      const float term = (ssq * LN2 - 2.0f * (float)m) / (float)(m - 1);
      atomicAdd(out, -term);
    }
  } else {
    const int i = (blockIdx.x - NCLS) * 256 + tid;
    const int c = (int)label[i];
    float v = 0.f;
    if (cnt[c] > 1)
      v = __builtin_amdgcn_logf(rowsum[i] - E2) * LN2;
#pragma unroll
    for (int off = 1; off < 64; off <<= 1) v += __shfl_xor(v, off);
    if (lane == 0) red[w] = v;
    __syncthreads();
    if (tid == 0)
      atomicAdd(out, red[0] + red[1] + red[2] + red[3]);
  }
}

extern "C" void kernel_launch(void* const* d_in, const int* in_sizes, int n_in,
                              void* d_out, int out_size, void* d_ws,
                              size_t ws_size, hipStream_t stream) {
  const float* emb = (const float*)d_in[0];
  const long long* label = (const long long*)d_in[1];
  float* out = (float*)d_out;

  char* ws = (char*)d_ws;
  unsigned short* abf = (unsigned short*)ws;           // 4 MB
  float* rowsum = (float*)(ws + (size_t)N * D * 2);    // N floats
  int* cnt = (int*)(rowsum + N);                       // 128 ints (100 used)
  int* list = cnt + 128;                               // NCLS*256 ints

  hipMemsetAsync(rowsum, 0, (size_t)N * 4 + 128 * 4, stream);
  hipMemsetAsync(out, 0, sizeof(float), stream);

  normalize_kernel<<<N / 4, 256, 0, stream>>>(emb, label, abf, cnt, list);

  // upper-triangle tiles: 64*65/2 = 2080 blocks, one 128x128 tile each
  simexp_rowsum_kernel<<<2080, 256, 0, stream>>>(abf, rowsum);

  finalize_kernel<<<NCLS + N / 256, 256, 0, stream>>>(abf, rowsum, label, cnt,
                                                      list, out);
}